// Round 11
// baseline (1216.964 us; speedup 1.0000x reference)
//
#include <hip/hip_runtime.h>
#include <hip/hip_fp16.h>
#include <math.h>

#define N_ING 100000
#define N_DIR 50000
#define NE    1000000
#define NDST_TOTAL 300000   // 50K(cooc)+50K(used)+100K(contains)+50K(pairs)+50K(follows)
#define NBUCK 4688          // ceil(300000/64): 64 dst nodes per bucket
#define BA    16            // hist/scatter blocks per edge type (r9-proven)
#define NBK   (5 * BA)      // 80
#define I4PT  (NE / 4)      // int4s per type
#define PB_ING 384
#define PB_DIR 192

typedef float v2f __attribute__((ext_vector_type(2)));

// ============ kA: bucket histogram (LDS atomics) + fused proj+score ========
__global__ __launch_bounds__(256) void kA_kernel(
    const int* __restrict__ e0, const int* __restrict__ e1,
    const int* __restrict__ e2, const int* __restrict__ e3,
    const int* __restrict__ e4, int* __restrict__ blockcnt,
    const float* __restrict__ x_ing, const float* __restrict__ W_pi,
    const float* __restrict__ b_pi,
    const float* __restrict__ as_cooc, const float* __restrict__ as_used,
    const float* __restrict__ ad_contains,
    unsigned* __restrict__ h8_ing, __half* __restrict__ s_ing,
    const float* __restrict__ x_dir, const float* __restrict__ W_pd,
    const float* __restrict__ b_pd,
    const float* __restrict__ ad_cooc, const float* __restrict__ ad_used,
    const float* __restrict__ as_contains, const float* __restrict__ as_pairs,
    const float* __restrict__ ad_pairs, const float* __restrict__ as_follows,
    const float* __restrict__ ad_follows,
    unsigned* __restrict__ h8_dir, __half* __restrict__ s_dir)
{
    __shared__ int hist[NBUCK];
    __shared__ float sW[16 * 64];
    __shared__ float sbb[64];
    __shared__ float satt[7 * 64];
    __shared__ float sx[4][16];
    __shared__ float srow[4][64];

    const int bid = blockIdx.x;
    const int tid = threadIdx.x;
    if (bid < NBK) {
        const int type = bid / BA, blk = bid % BA;
        const int* ei = type == 0 ? e0 : type == 1 ? e1 : type == 2 ? e2
                      : type == 3 ? e3 : e4;
        const int base = type == 0 ? 0 : type == 1 ? 50000 : type == 2 ? 100000
                       : type == 3 ? 200000 : 250000;
        for (int i = tid; i < NBUCK; i += 256) hist[i] = 0;
        __syncthreads();
        const int4* d4 = (const int4*)(ei + NE);
        for (int i = blk * 256 + tid; i < I4PT; i += BA * 256) {
            int4 d = d4[i];
            atomicAdd(&hist[(base + d.x) >> 6], 1);
            atomicAdd(&hist[(base + d.y) >> 6], 1);
            atomicAdd(&hist[(base + d.z) >> 6], 1);
            atomicAdd(&hist[(base + d.w) >> 6], 1);
        }
        __syncthreads();
        int* row = blockcnt + (size_t)bid * NBUCK;
        for (int i = tid; i < NBUCK; i += 256) row[i] = hist[i];
    } else if (bid < NBK + PB_ING) {
        const int g = tid >> 6, t = tid & 63;
        for (int i = tid; i < 16 * 64; i += 256) sW[i] = W_pi[i];
        if (tid < 64) {
            sbb[tid] = b_pi[tid];
            satt[tid]       = as_cooc[tid];
            satt[64 + tid]  = as_used[tid];
            satt[128 + tid] = ad_contains[tid];
        }
        __syncthreads();
        for (int q = bid - NBK; q < N_ING / 4; q += PB_ING) {
            int n = q * 4 + g;
            if (t < 16) sx[g][t] = x_ing[(size_t)n * 16 + t];
            __syncthreads();
            float s = sbb[t];
#pragma unroll
            for (int i = 0; i < 16; ++i) s += sx[g][i] * sW[i * 64 + t];
            srow[g][t] = s;
            __syncthreads();
            if (t < 16) {
                int w0 = __builtin_amdgcn_cvt_pk_fp8_f32(srow[g][t * 4], srow[g][t * 4 + 1], 0, false);
                int w  = __builtin_amdgcn_cvt_pk_fp8_f32(srow[g][t * 4 + 2], srow[g][t * 4 + 3], w0, true);
                h8_ing[(size_t)n * 16 + t] = (unsigned)w;
            }
            if (t < 12) {
                int slot = t >> 2, hh = t & 3;
                float sc = 0.f;
#pragma unroll
                for (int d = 0; d < 16; ++d)
                    sc += srow[g][hh * 16 + d] * satt[slot * 64 + hh * 16 + d];
                s_ing[(size_t)n * 12 + t] = __float2half(sc);
            }
            __syncthreads();
        }
    } else {
        const int g = tid >> 6, t = tid & 63;
        for (int i = tid; i < 8 * 64; i += 256) sW[i] = W_pd[i];
        if (tid < 64) {
            sbb[tid] = b_pd[tid];
            satt[tid]        = ad_cooc[tid];
            satt[64  + tid]  = ad_used[tid];
            satt[128 + tid]  = as_contains[tid];
            satt[192 + tid]  = as_pairs[tid];
            satt[256 + tid]  = ad_pairs[tid];
            satt[320 + tid]  = as_follows[tid];
            satt[384 + tid]  = ad_follows[tid];
        }
        __syncthreads();
        for (int q = bid - NBK - PB_ING; q < N_DIR / 4; q += PB_DIR) {
            int n = q * 4 + g;
            if (t < 8) sx[g][t] = x_dir[(size_t)n * 8 + t];
            __syncthreads();
            float s = sbb[t];
#pragma unroll
            for (int i = 0; i < 8; ++i) s += sx[g][i] * sW[i * 64 + t];
            srow[g][t] = s;
            __syncthreads();
            if (t < 16) {
                int w0 = __builtin_amdgcn_cvt_pk_fp8_f32(srow[g][t * 4], srow[g][t * 4 + 1], 0, false);
                int w  = __builtin_amdgcn_cvt_pk_fp8_f32(srow[g][t * 4 + 2], srow[g][t * 4 + 3], w0, true);
                h8_dir[(size_t)n * 16 + t] = (unsigned)w;
            }
            if (t < 28) {
                int slot = t >> 2, hh = t & 3;
                float sc = 0.f;
#pragma unroll
                for (int d = 0; d < 16; ++d)
                    sc += srow[g][hh * 16 + d] * satt[slot * 64 + hh * 16 + d];
                s_dir[(size_t)n * 28 + t] = __float2half(sc);
            }
            __syncthreads();
        }
    }
}

// ============ k2: bucket totals + bases, 64 buckets x 4 threads per block ==
__global__ __launch_bounds__(256) void k2_kernel(
    const int* __restrict__ blockcnt, int* __restrict__ blockbase,
    int* __restrict__ bbase, int* __restrict__ btot, int* __restrict__ cursor)
{
    __shared__ int part[4][64];
    __shared__ int tots[64];
    __shared__ int scn[64];
    __shared__ int bw;
    const int tid = threadIdx.x;
    const int kq = tid >> 6, bl = tid & 63;   // 4 k-quarters x 64 buckets
    const int b = blockIdx.x * 64 + bl;
    const int K = NBK / 4;                    // 20 rows per quarter
    int ps = 0;
    if (b < NBUCK)
        for (int k = kq * K; k < kq * K + K; ++k)
            ps += blockcnt[(size_t)k * NBUCK + b];
    part[kq][bl] = ps;
    __syncthreads();
    if (tid < 64) {
        int t = part[0][tid] + part[1][tid] + part[2][tid] + part[3][tid];
        tots[tid] = t;
        scn[tid] = t;
    }
    __syncthreads();
    for (int off = 1; off < 64; off <<= 1) {
        int v = 0;
        if (tid < 64 && tid >= off) v = scn[tid - off];
        __syncthreads();
        if (tid < 64) scn[tid] += v;
        __syncthreads();
    }
    if (tid == 63) bw = atomicAdd(cursor, scn[63]);
    __syncthreads();
    if (b < NBUCK) {
        int bs = bw + scn[bl] - tots[bl];     // exclusive bucket base
        if (kq == 0) {
            bbase[b] = bs;
            btot[b] = tots[bl];
        }
        int run = bs;
        for (int q = 0; q < kq; ++q) run += part[q][bl];
        for (int k = kq * K; k < kq * K + K; ++k) {
            blockbase[(size_t)k * NBUCK + b] = run;
            run += blockcnt[(size_t)k * NBUCK + b];
        }
    }
}

// ============ k3: bucket scatter (LDS cursors, packed u32 entries) =========
__global__ __launch_bounds__(256) void k3_kernel(
    const int* __restrict__ e0, const int* __restrict__ e1,
    const int* __restrict__ e2, const int* __restrict__ e3,
    const int* __restrict__ e4, const int* __restrict__ blockbase,
    unsigned* __restrict__ bpair)
{
    __shared__ int cur[NBUCK];
    const int bid = blockIdx.x, tid = threadIdx.x;
    const int type = bid / BA, blk = bid % BA;
    const int* ei = type == 0 ? e0 : type == 1 ? e1 : type == 2 ? e2
                  : type == 3 ? e3 : e4;
    const int base = type == 0 ? 0 : type == 1 ? 50000 : type == 2 ? 100000
                   : type == 3 ? 200000 : 250000;
    const int* row = blockbase + (size_t)bid * NBUCK;
    for (int i = tid; i < NBUCK; i += 256) cur[i] = row[i];
    __syncthreads();
    const int4* s4 = (const int4*)ei;
    const int4* d4 = (const int4*)(ei + NE);
    for (int i = blk * 256 + tid; i < I4PT; i += BA * 256) {
        int4 s = s4[i];
        int4 d = d4[i];
        int g0 = base + d.x, g1 = base + d.y, g2 = base + d.z, g3 = base + d.w;
        int p0 = atomicAdd(&cur[g0 >> 6], 1);
        int p1 = atomicAdd(&cur[g1 >> 6], 1);
        int p2 = atomicAdd(&cur[g2 >> 6], 1);
        int p3 = atomicAdd(&cur[g3 >> 6], 1);
        bpair[p0] = ((unsigned)(g0 & 63) << 17) | (unsigned)s.x;
        bpair[p1] = ((unsigned)(g1 & 63) << 17) | (unsigned)s.y;
        bpair[p2] = ((unsigned)(g2 & 63) << 17) | (unsigned)s.z;
        bpair[p3] = ((unsigned)(g3 & 63) << 17) | (unsigned)s.w;
    }
}

// ============ k4: per-bucket counting sort, wave-privatized histograms =====
__global__ __launch_bounds__(256) void k4_kernel(
    const unsigned* __restrict__ bpair, const int* __restrict__ bbase,
    const int* __restrict__ btot, int* __restrict__ perm,
    int* __restrict__ start, int* __restrict__ cnt)
{
    __shared__ int hw[4][64];   // per-wave histograms
    __shared__ int sc[64];      // exclusive scan of totals
    __shared__ int cuw[4][64];  // per-wave placement cursors
    const int b = blockIdx.x, tid = threadIdx.x;
    const int w = tid >> 6;
    const int jb = bbase[b], n = btot[b];
    hw[tid >> 6][tid & 63] = 0;
    __syncthreads();
    for (int i = tid; i < n; i += 256)
        atomicAdd(&hw[w][bpair[jb + i] >> 17], 1);
    __syncthreads();
    if (tid == 0) {
        int r = 0;
        for (int i = 0; i < 64; ++i) {
            int h0 = hw[0][i], h1 = hw[1][i], h2 = hw[2][i], h3 = hw[3][i];
            sc[i] = r;
            cuw[0][i] = r;
            cuw[1][i] = r + h0;
            cuw[2][i] = r + h0 + h1;
            cuw[3][i] = r + h0 + h1 + h2;
            r += h0 + h1 + h2 + h3;
        }
    }
    __syncthreads();
    if (tid < 64) {
        int dg = b * 64 + tid;
        if (dg < NDST_TOTAL) {
            start[dg] = jb + sc[tid];
            int nx = (tid < 63) ? sc[tid + 1] : n;
            cnt[dg] = nx - sc[tid];
        }
    }
    for (int i = tid; i < n; i += 256) {
        unsigned p = bpair[jb + i];
        int pos = atomicAdd(&cuw[w][p >> 17], 1);
        perm[jb + pos] = (int)(p & 0x1FFFF);
    }
}

// ============ agg: fp8 rows, fp16 scores, 4-row-batched LDS matvec =========
// each wave owns a contiguous chunk of segments (better perm locality);
// dir-segment v rows buffered in srow4, semantic matvec amortized x4
__global__ __launch_bounds__(256) void agg_all_kernel(
    const int* __restrict__ perm, const int* __restrict__ start,
    const int* __restrict__ cnttot,
    const unsigned* __restrict__ h8_ing, const unsigned* __restrict__ h8_dir,
    const __half* __restrict__ s_ing, const __half* __restrict__ s_dir,
    const float* __restrict__ Wk, const float* __restrict__ bk,
    float* __restrict__ pool_ing, float* __restrict__ pool_dir,
    float* __restrict__ sem_dir)
{
    __shared__ float sWk[64 * 64];      // 16 KB
    __shared__ float srow4[4][4][64];   // [wave][slot][feat] 4 KB
    __shared__ float sred[4][64];       // 1 KB
    const int t = threadIdx.x & 63, w = threadIdx.x >> 6;
    const int g  = t >> 4;       // edge group 0..3
    const int l4 = t & 15;       // feature quad: 4*l4 .. 4*l4+3
    const int hq = l4 >> 2;      // head of my features
    for (int i = threadIdx.x; i < 4096; i += 256) sWk[i] = Wk[i];
    const float bkf = bk[t];
    float p_ing = 0.f;
    float p0 = 0.f, p1 = 0.f, p2 = 0.f, p3 = 0.f;
    float m0 = 0.f, m1 = 0.f, m2 = 0.f, m3 = 0.f;
    __syncthreads();

    const int nwaves = gridDim.x * 4;
    const int wave_id = blockIdx.x * 4 + w;
    const int spw = (NDST_TOTAL + nwaves - 1) / nwaves;
    const int dlo = wave_id * spw;
    const int dhi = min(dlo + spw, NDST_TOTAL);

    int nb = 0;
    int btype[4];

    for (int d = dlo; d < dhi; ++d) {
        int type, ld;
        const __half *ssrc, *sdst;
        const unsigned* hsrc;
        int ss, soff, ds, doff;
        if (d < 50000)       { type = 0; ld = d;          ssrc = s_ing; ss = 12; soff = 0;  sdst = s_dir; ds = 28; doff = 0;  hsrc = h8_ing; }
        else if (d < 100000) { type = 1; ld = d - 50000;  ssrc = s_ing; ss = 12; soff = 4;  sdst = s_dir; ds = 28; doff = 4;  hsrc = h8_ing; }
        else if (d < 200000) { type = 2; ld = d - 100000; ssrc = s_dir; ss = 28; soff = 8;  sdst = s_ing; ds = 12; doff = 8;  hsrc = h8_dir; }
        else if (d < 250000) { type = 3; ld = d - 200000; ssrc = s_dir; ss = 28; soff = 12; sdst = s_dir; ds = 28; doff = 16; hsrc = h8_dir; }
        else                 { type = 4; ld = d - 250000; ssrc = s_dir; ss = 28; soff = 20; sdst = s_dir; ds = 28; doff = 24; hsrc = h8_dir; }
        float adst = __half2float(sdst[(size_t)ld * ds + doff + hq]);
        int jb = start[d], je = jb + cnttot[d];
        float4 acc = make_float4(0.f, 0.f, 0.f, 0.f);
        float dsum = 0.f;
        for (int j = jb; j < je; j += 8) {
            int j0 = j + g, j1 = j + 4 + g;
            bool v0 = j0 < je, v1 = j1 < je;
            int s0 = perm[v0 ? j0 : je - 1];
            int s1 = perm[v1 ? j1 : je - 1];
            float c0 = __half2float(ssrc[(size_t)s0 * ss + soff + hq]);
            float c1 = __half2float(ssrc[(size_t)s1 * ss + soff + hq]);
            unsigned u0 = hsrc[(size_t)s0 * 16 + l4];
            unsigned u1 = hsrc[(size_t)s1 * 16 + l4];
            float a0 = c0 + adst; a0 = a0 > 0.f ? a0 : 0.2f * a0;
            float a1 = c1 + adst; a1 = a1 > 0.f ? a1 : 0.2f * a1;
            float e0 = v0 ? __expf(a0) : 0.f;
            float e1 = v1 ? __expf(a1) : 0.f;
            dsum += e0 + e1;
            v2f lo0 = __builtin_amdgcn_cvt_pk_f32_fp8((int)u0, false);
            v2f hi0 = __builtin_amdgcn_cvt_pk_f32_fp8((int)u0, true);
            v2f lo1 = __builtin_amdgcn_cvt_pk_f32_fp8((int)u1, false);
            v2f hi1 = __builtin_amdgcn_cvt_pk_f32_fp8((int)u1, true);
            acc.x += lo0.x * e0 + lo1.x * e1;
            acc.y += lo0.y * e0 + lo1.y * e1;
            acc.z += hi0.x * e0 + hi1.x * e1;
            acc.w += hi0.y * e0 + hi1.y * e1;
        }
#pragma unroll
        for (int mask = 16; mask <= 32; mask <<= 1) {
            acc.x += __shfl_xor(acc.x, mask, 64);
            acc.y += __shfl_xor(acc.y, mask, 64);
            acc.z += __shfl_xor(acc.z, mask, 64);
            acc.w += __shfl_xor(acc.w, mask, 64);
            dsum  += __shfl_xor(dsum,  mask, 64);
        }
        float inv = 1.f / (dsum + 1e-16f);
        float4 v4 = make_float4(fmaxf(acc.x * inv, 0.f), fmaxf(acc.y * inv, 0.f),
                                fmaxf(acc.z * inv, 0.f), fmaxf(acc.w * inv, 0.f));
        if (g == 0) *(float4*)&srow4[w][nb][l4 * 4] = v4;   // wave-coherent
        if (type == 2) {
            p_ing += srow4[w][nb][t];
        } else {
            btype[nb] = type;
            ++nb;
            if (nb == 4) {
                // batched matvec: 4 rows share each sWk read
                float a20 = bkf, a21 = bkf, a22 = bkf, a23 = bkf;
#pragma unroll
                for (int kc = 0; kc < 16; ++kc) {
                    float w0 = sWk[(kc * 4 + 0) * 64 + t];
                    float w1 = sWk[(kc * 4 + 1) * 64 + t];
                    float w2 = sWk[(kc * 4 + 2) * 64 + t];
                    float w3 = sWk[(kc * 4 + 3) * 64 + t];
                    float4 r0 = *(float4*)&srow4[w][0][kc * 4];
                    float4 r1 = *(float4*)&srow4[w][1][kc * 4];
                    float4 r2 = *(float4*)&srow4[w][2][kc * 4];
                    float4 r3 = *(float4*)&srow4[w][3][kc * 4];
                    a20 += r0.x * w0 + r0.y * w1 + r0.z * w2 + r0.w * w3;
                    a21 += r1.x * w0 + r1.y * w1 + r1.z * w2 + r1.w * w3;
                    a22 += r2.x * w0 + r2.y * w1 + r2.z * w2 + r2.w * w3;
                    a23 += r3.x * w0 + r3.y * w1 + r3.z * w2 + r3.w * w3;
                }
                float a2v[4] = { a20, a21, a22, a23 };
#pragma unroll
                for (int r = 0; r < 4; ++r) {
                    float tv = tanhf(a2v[r]);
                    float vr = srow4[w][r][t];
                    int ty = btype[r];
                    if (ty == 0)      { p0 += vr; m0 += tv; }
                    else if (ty == 1) { p1 += vr; m1 += tv; }
                    else if (ty == 3) { p2 += vr; m2 += tv; }
                    else              { p3 += vr; m3 += tv; }
                }
                nb = 0;
            }
        }
    }
    // flush remaining buffered rows (0..3)
    if (nb > 0) {
        float a20 = bkf, a21 = bkf, a22 = bkf, a23 = bkf;
#pragma unroll
        for (int kc = 0; kc < 16; ++kc) {
            float w0 = sWk[(kc * 4 + 0) * 64 + t];
            float w1 = sWk[(kc * 4 + 1) * 64 + t];
            float w2 = sWk[(kc * 4 + 2) * 64 + t];
            float w3 = sWk[(kc * 4 + 3) * 64 + t];
            float4 r0 = *(float4*)&srow4[w][0][kc * 4];
            float4 r1 = *(float4*)&srow4[w][1][kc * 4];
            float4 r2 = *(float4*)&srow4[w][2][kc * 4];
            float4 r3 = *(float4*)&srow4[w][3][kc * 4];
            a20 += r0.x * w0 + r0.y * w1 + r0.z * w2 + r0.w * w3;
            a21 += r1.x * w0 + r1.y * w1 + r1.z * w2 + r1.w * w3;
            a22 += r2.x * w0 + r2.y * w1 + r2.z * w2 + r2.w * w3;
            a23 += r3.x * w0 + r3.y * w1 + r3.z * w2 + r3.w * w3;
        }
        float a2v[4] = { a20, a21, a22, a23 };
#pragma unroll
        for (int r = 0; r < 4; ++r) {
            if (r < nb) {
                float tv = tanhf(a2v[r]);
                float vr = srow4[w][r][t];
                int ty = btype[r];
                if (ty == 0)      { p0 += vr; m0 += tv; }
                else if (ty == 1) { p1 += vr; m1 += tv; }
                else if (ty == 3) { p2 += vr; m2 += tv; }
                else              { p3 += vr; m3 += tv; }
            }
        }
    }

    float vals[9] = { p_ing, p0, p1, p2, p3, m0, m1, m2, m3 };
    float* outs[9] = { pool_ing, pool_dir, pool_dir + 64, pool_dir + 128,
                       pool_dir + 192, sem_dir, sem_dir + 64, sem_dir + 128,
                       sem_dir + 192 };
    for (int i = 0; i < 9; ++i) {
        __syncthreads();
        sred[w][t] = vals[i];
        __syncthreads();
        if (w == 0)
            atomicAdd(&outs[i][t], sred[0][t] + sred[1][t] + sred[2][t] + sred[3][t]);
    }
}

// ============ final: semantic softmax + pools + VAE head ===================
__global__ __launch_bounds__(64) void final_kernel(
    const float* __restrict__ pool_ing, const float* __restrict__ pool_dir,
    const float* __restrict__ sem_dir, const float* __restrict__ q,
    const float* __restrict__ cond, const float* __restrict__ eps,
    const float* __restrict__ W_mu, const float* __restrict__ b_mu,
    const float* __restrict__ W_lv, const float* __restrict__ b_lv,
    const float* __restrict__ W_fc3, const float* __restrict__ b_fc3,
    const float* __restrict__ W_fc2, const float* __restrict__ b_fc2,
    float* __restrict__ out)
{
    __shared__ float gr[136];
    __shared__ float sc[4], attn[4];
    __shared__ float z[32], hfc[64];
    int t = threadIdx.x;  // 64 threads
    if (t < 4) {
        float s = 0.f;
        for (int f = 0; f < 64; ++f)
            s += (sem_dir[t * 64 + f] / (float)N_DIR) * q[f];
        sc[t] = s;
    }
    gr[t] = pool_ing[t] / (float)N_ING;   // out_ing == o_cont (T=1 softmax)
    __syncthreads();
    if (t == 0) {
        float m = fmaxf(fmaxf(sc[0], sc[1]), fmaxf(sc[2], sc[3]));
        float ssum = 0.f;
        for (int i = 0; i < 4; ++i) { attn[i] = expf(sc[i] - m); ssum += attn[i]; }
        for (int i = 0; i < 4; ++i) attn[i] /= ssum;
    }
    __syncthreads();
    {
        float v = 0.f;
        for (int tt = 0; tt < 4; ++tt)
            v += attn[tt] * (pool_dir[tt * 64 + t] / (float)N_DIR);
        gr[64 + t] = v;
    }
    if (t < 8) gr[128 + t] = cond[t];
    __syncthreads();
    if (t < 32) {
        float m = b_mu[t], lv = b_lv[t];
        for (int i = 0; i < 136; ++i) {
            float g = gr[i];
            m  += g * W_mu[i * 32 + t];
            lv += g * W_lv[i * 32 + t];
        }
        out[16 + t] = m;
        out[48 + t] = lv;
        z[t] = m + eps[t] * expf(0.5f * lv);
    }
    __syncthreads();
    {
        float v = b_fc3[t];
        for (int j = 0; j < 32; ++j) v += z[j] * W_fc3[j * 64 + t];
        hfc[t] = fmaxf(v, 0.f);
    }
    __syncthreads();
    if (t < 16) {
        float v = b_fc2[t];
        for (int f = 0; f < 64; ++f) v += hfc[f] * W_fc2[f * 16 + t];
        out[t] = tanhf(v);
    }
}

extern "C" void kernel_launch(void* const* d_in, const int* in_sizes, int n_in,
                              void* d_out, int out_size, void* d_ws, size_t ws_size,
                              hipStream_t stream) {
    const float* x_ing = (const float*)d_in[0];
    const float* x_dir = (const float*)d_in[1];
    const float* cond  = (const float*)d_in[2];
    const float* eps   = (const float*)d_in[3];
    const int* ei_cooc     = (const int*)d_in[4];
    const int* ei_used     = (const int*)d_in[5];
    const int* ei_contains = (const int*)d_in[6];
    const int* ei_pairs    = (const int*)d_in[7];
    const int* ei_follows  = (const int*)d_in[8];
    const float* W_pi = (const float*)d_in[9];
    const float* b_pi = (const float*)d_in[10];
    const float* W_pd = (const float*)d_in[11];
    const float* b_pd = (const float*)d_in[12];
    const float* Wk   = (const float*)d_in[13];
    const float* bk   = (const float*)d_in[14];
    const float* q    = (const float*)d_in[15];
    const float* W_mu = (const float*)d_in[16];
    const float* b_mu = (const float*)d_in[17];
    const float* W_lv = (const float*)d_in[18];
    const float* b_lv = (const float*)d_in[19];
    const float* W_fc3 = (const float*)d_in[20];
    const float* b_fc3 = (const float*)d_in[21];
    const float* W_fc2 = (const float*)d_in[22];
    const float* b_fc2 = (const float*)d_in[23];
    const float* as_cooc     = (const float*)d_in[24];
    const float* ad_cooc     = (const float*)d_in[25];
    const float* as_used     = (const float*)d_in[26];
    const float* ad_used     = (const float*)d_in[27];
    const float* as_contains = (const float*)d_in[28];
    const float* ad_contains = (const float*)d_in[29];
    const float* as_pairs    = (const float*)d_in[30];
    const float* ad_pairs    = (const float*)d_in[31];
    const float* as_follows  = (const float*)d_in[32];
    const float* ad_follows  = (const float*)d_in[33];

    // ---- workspace layout ----
    unsigned* bpair = (unsigned*)d_ws;                        // 5M u32 (20 MB)
    unsigned* h8_ing = bpair + (size_t)5 * NE;                // N_ING*16 u32
    unsigned* h8_dir = h8_ing + (size_t)N_ING * 16;           // N_DIR*16
    __half* s_ing = (__half*)(h8_dir + (size_t)N_DIR * 16);   // N_ING*12 fp16
    __half* s_dir = s_ing + (size_t)N_ING * 12;               // N_DIR*28 fp16
    int*   perm  = (int*)(s_dir + (size_t)N_DIR * 28);        // 5M
    int*   blockcnt  = perm + (size_t)5 * NE;                 // 80*4688
    int*   blockbase = blockcnt + (size_t)NBK * NBUCK;        // 80*4688
    int*   bbase  = blockbase + (size_t)NBK * NBUCK;          // 4688
    int*   btot   = bbase + NBUCK;                            // 4688
    int*   start  = btot + NBUCK;                             // 300K
    int*   cnt    = start + NDST_TOTAL;                       // 300K
    int*   cursor = cnt + NDST_TOTAL;                         // 1  (zeroed region)
    float* pool_ing = (float*)(cursor + 1);                   // 64
    float* pool_dir = pool_ing + 64;                          // 4*64
    float* sem_dir  = pool_dir + 256;                         // 4*64

    // tiny memset: cursor + pools
    hipMemsetAsync(cursor, 0, (1 + 64 + 256 + 256) * sizeof(int), stream);

    // kA: bucket histogram (LDS-only atomics) + fused proj/fp8/fp16-score
    kA_kernel<<<NBK + PB_ING + PB_DIR, 256, 0, stream>>>(
        ei_cooc, ei_used, ei_contains, ei_pairs, ei_follows, blockcnt,
        x_ing, W_pi, b_pi, as_cooc, as_used, ad_contains, h8_ing, s_ing,
        x_dir, W_pd, b_pd, ad_cooc, ad_used, as_contains, as_pairs, ad_pairs,
        as_follows, ad_follows, h8_dir, s_dir);

    // k2: bucket scan -> bases (64 buckets x 4 threads per block)
    k2_kernel<<<(NBUCK + 63) / 64, 256, 0, stream>>>(
        blockcnt, blockbase, bbase, btot, cursor);

    // k3: bucket scatter (LDS cursors, u32 packed)
    k3_kernel<<<NBK, 256, 0, stream>>>(
        ei_cooc, ei_used, ei_contains, ei_pairs, ei_follows, blockbase, bpair);

    // k4: per-bucket counting sort -> perm + start/cnt
    k4_kernel<<<NBUCK, 256, 0, stream>>>(bpair, bbase, btot, perm, start, cnt);

    // agg over all 300K dst segments (contiguous chunks per wave)
    agg_all_kernel<<<2048, 256, 0, stream>>>(
        perm, start, cnt, h8_ing, h8_dir, s_ing, s_dir, Wk, bk,
        pool_ing, pool_dir, sem_dir);

    final_kernel<<<1, 64, 0, stream>>>(
        pool_ing, pool_dir, sem_dir, q, cond, eps,
        W_mu, b_mu, W_lv, b_lv, W_fc3, b_fc3, W_fc2, b_fc2, (float*)d_out);
}

// Round 12
// 606.083 us; speedup vs baseline: 2.0079x; 2.0079x over previous
//
#include <hip/hip_runtime.h>
#include <hip/hip_fp16.h>
#include <math.h>

#define N_ING 100000
#define N_DIR 50000
#define NE    1000000
#define NDST_TOTAL 300000   // 50K(cooc)+50K(used)+100K(contains)+50K(pairs)+50K(follows)
#define NBUCK 4688          // ceil(300000/64): 64 dst nodes per bucket
#define BA    16            // hist/scatter blocks per edge type (proven in 493us run)
#define NBK   (5 * BA)      // 80
#define I4PT  (NE / 4)      // int4s per type
#define PB_ING 384
#define PB_DIR 192

typedef float v2f __attribute__((ext_vector_type(2)));

// ============ kA: bucket histogram (LDS atomics) + fused proj+score ========
__global__ __launch_bounds__(256) void kA_kernel(
    const int* __restrict__ e0, const int* __restrict__ e1,
    const int* __restrict__ e2, const int* __restrict__ e3,
    const int* __restrict__ e4, int* __restrict__ blockcnt,
    const float* __restrict__ x_ing, const float* __restrict__ W_pi,
    const float* __restrict__ b_pi,
    const float* __restrict__ as_cooc, const float* __restrict__ as_used,
    const float* __restrict__ ad_contains,
    unsigned* __restrict__ h8_ing, __half* __restrict__ s_ing,
    const float* __restrict__ x_dir, const float* __restrict__ W_pd,
    const float* __restrict__ b_pd,
    const float* __restrict__ ad_cooc, const float* __restrict__ ad_used,
    const float* __restrict__ as_contains, const float* __restrict__ as_pairs,
    const float* __restrict__ ad_pairs, const float* __restrict__ as_follows,
    const float* __restrict__ ad_follows,
    unsigned* __restrict__ h8_dir, __half* __restrict__ s_dir)
{
    __shared__ int hist[NBUCK];
    __shared__ float sW[16 * 64];
    __shared__ float sbb[64];
    __shared__ float satt[7 * 64];
    __shared__ float sx[4][16];
    __shared__ float srow[4][64];

    const int bid = blockIdx.x;
    const int tid = threadIdx.x;
    if (bid < NBK) {
        const int type = bid / BA, blk = bid % BA;
        const int* ei = type == 0 ? e0 : type == 1 ? e1 : type == 2 ? e2
                      : type == 3 ? e3 : e4;
        const int base = type == 0 ? 0 : type == 1 ? 50000 : type == 2 ? 100000
                       : type == 3 ? 200000 : 250000;
        for (int i = tid; i < NBUCK; i += 256) hist[i] = 0;
        __syncthreads();
        const int4* d4 = (const int4*)(ei + NE);
        for (int i = blk * 256 + tid; i < I4PT; i += BA * 256) {
            int4 d = d4[i];
            atomicAdd(&hist[(base + d.x) >> 6], 1);
            atomicAdd(&hist[(base + d.y) >> 6], 1);
            atomicAdd(&hist[(base + d.z) >> 6], 1);
            atomicAdd(&hist[(base + d.w) >> 6], 1);
        }
        __syncthreads();
        int* row = blockcnt + (size_t)bid * NBUCK;
        for (int i = tid; i < NBUCK; i += 256) row[i] = hist[i];
    } else if (bid < NBK + PB_ING) {
        const int g = tid >> 6, t = tid & 63;
        for (int i = tid; i < 16 * 64; i += 256) sW[i] = W_pi[i];
        if (tid < 64) {
            sbb[tid] = b_pi[tid];
            satt[tid]       = as_cooc[tid];
            satt[64 + tid]  = as_used[tid];
            satt[128 + tid] = ad_contains[tid];
        }
        __syncthreads();
        for (int q = bid - NBK; q < N_ING / 4; q += PB_ING) {
            int n = q * 4 + g;
            if (t < 16) sx[g][t] = x_ing[(size_t)n * 16 + t];
            __syncthreads();
            float s = sbb[t];
#pragma unroll
            for (int i = 0; i < 16; ++i) s += sx[g][i] * sW[i * 64 + t];
            srow[g][t] = s;
            __syncthreads();
            if (t < 16) {
                int w0 = __builtin_amdgcn_cvt_pk_fp8_f32(srow[g][t * 4], srow[g][t * 4 + 1], 0, false);
                int w  = __builtin_amdgcn_cvt_pk_fp8_f32(srow[g][t * 4 + 2], srow[g][t * 4 + 3], w0, true);
                h8_ing[(size_t)n * 16 + t] = (unsigned)w;
            }
            if (t < 12) {
                int slot = t >> 2, hh = t & 3;
                float sc = 0.f;
#pragma unroll
                for (int d = 0; d < 16; ++d)
                    sc += srow[g][hh * 16 + d] * satt[slot * 64 + hh * 16 + d];
                s_ing[(size_t)n * 12 + t] = __float2half(sc);
            }
            __syncthreads();
        }
    } else {
        const int g = tid >> 6, t = tid & 63;
        for (int i = tid; i < 8 * 64; i += 256) sW[i] = W_pd[i];
        if (tid < 64) {
            sbb[tid] = b_pd[tid];
            satt[tid]        = ad_cooc[tid];
            satt[64  + tid]  = ad_used[tid];
            satt[128 + tid]  = as_contains[tid];
            satt[192 + tid]  = as_pairs[tid];
            satt[256 + tid]  = ad_pairs[tid];
            satt[320 + tid]  = as_follows[tid];
            satt[384 + tid]  = ad_follows[tid];
        }
        __syncthreads();
        for (int q = bid - NBK - PB_ING; q < N_DIR / 4; q += PB_DIR) {
            int n = q * 4 + g;
            if (t < 8) sx[g][t] = x_dir[(size_t)n * 8 + t];
            __syncthreads();
            float s = sbb[t];
#pragma unroll
            for (int i = 0; i < 8; ++i) s += sx[g][i] * sW[i * 64 + t];
            srow[g][t] = s;
            __syncthreads();
            if (t < 16) {
                int w0 = __builtin_amdgcn_cvt_pk_fp8_f32(srow[g][t * 4], srow[g][t * 4 + 1], 0, false);
                int w  = __builtin_amdgcn_cvt_pk_fp8_f32(srow[g][t * 4 + 2], srow[g][t * 4 + 3], w0, true);
                h8_dir[(size_t)n * 16 + t] = (unsigned)w;
            }
            if (t < 28) {
                int slot = t >> 2, hh = t & 3;
                float sc = 0.f;
#pragma unroll
                for (int d = 0; d < 16; ++d)
                    sc += srow[g][hh * 16 + d] * satt[slot * 64 + hh * 16 + d];
                s_dir[(size_t)n * 28 + t] = __float2half(sc);
            }
            __syncthreads();
        }
    }
}

// ============ k2: bucket totals + bases, 64 buckets x 4 threads per block ==
__global__ __launch_bounds__(256) void k2_kernel(
    const int* __restrict__ blockcnt, int* __restrict__ blockbase,
    int* __restrict__ bbase, int* __restrict__ btot, int* __restrict__ cursor)
{
    __shared__ int part[4][64];
    __shared__ int tots[64];
    __shared__ int scn[64];
    __shared__ int bw;
    const int tid = threadIdx.x;
    const int kq = tid >> 6, bl = tid & 63;   // 4 k-quarters x 64 buckets
    const int b = blockIdx.x * 64 + bl;
    const int K = NBK / 4;                    // 20 rows per quarter
    int ps = 0;
    if (b < NBUCK)
        for (int k = kq * K; k < kq * K + K; ++k)
            ps += blockcnt[(size_t)k * NBUCK + b];
    part[kq][bl] = ps;
    __syncthreads();
    if (tid < 64) {
        int t = part[0][tid] + part[1][tid] + part[2][tid] + part[3][tid];
        tots[tid] = t;
        scn[tid] = t;
    }
    __syncthreads();
    for (int off = 1; off < 64; off <<= 1) {
        int v = 0;
        if (tid < 64 && tid >= off) v = scn[tid - off];
        __syncthreads();
        if (tid < 64) scn[tid] += v;
        __syncthreads();
    }
    if (tid == 63) bw = atomicAdd(cursor, scn[63]);
    __syncthreads();
    if (b < NBUCK) {
        int bs = bw + scn[bl] - tots[bl];     // exclusive bucket base
        if (kq == 0) {
            bbase[b] = bs;
            btot[b] = tots[bl];
        }
        int run = bs;
        for (int q = 0; q < kq; ++q) run += part[q][bl];
        for (int k = kq * K; k < kq * K + K; ++k) {
            blockbase[(size_t)k * NBUCK + b] = run;
            run += blockcnt[(size_t)k * NBUCK + b];
        }
    }
}

// ============ k3: bucket scatter (LDS cursors, packed u32 entries) =========
__global__ __launch_bounds__(256) void k3_kernel(
    const int* __restrict__ e0, const int* __restrict__ e1,
    const int* __restrict__ e2, const int* __restrict__ e3,
    const int* __restrict__ e4, const int* __restrict__ blockbase,
    unsigned* __restrict__ bpair)
{
    __shared__ int cur[NBUCK];
    const int bid = blockIdx.x, tid = threadIdx.x;
    const int type = bid / BA, blk = bid % BA;
    const int* ei = type == 0 ? e0 : type == 1 ? e1 : type == 2 ? e2
                  : type == 3 ? e3 : e4;
    const int base = type == 0 ? 0 : type == 1 ? 50000 : type == 2 ? 100000
                   : type == 3 ? 200000 : 250000;
    const int* row = blockbase + (size_t)bid * NBUCK;
    for (int i = tid; i < NBUCK; i += 256) cur[i] = row[i];
    __syncthreads();
    const int4* s4 = (const int4*)ei;
    const int4* d4 = (const int4*)(ei + NE);
    for (int i = blk * 256 + tid; i < I4PT; i += BA * 256) {
        int4 s = s4[i];
        int4 d = d4[i];
        int g0 = base + d.x, g1 = base + d.y, g2 = base + d.z, g3 = base + d.w;
        int p0 = atomicAdd(&cur[g0 >> 6], 1);
        int p1 = atomicAdd(&cur[g1 >> 6], 1);
        int p2 = atomicAdd(&cur[g2 >> 6], 1);
        int p3 = atomicAdd(&cur[g3 >> 6], 1);
        bpair[p0] = ((unsigned)(g0 & 63) << 17) | (unsigned)s.x;
        bpair[p1] = ((unsigned)(g1 & 63) << 17) | (unsigned)s.y;
        bpair[p2] = ((unsigned)(g2 & 63) << 17) | (unsigned)s.z;
        bpair[p3] = ((unsigned)(g3 & 63) << 17) | (unsigned)s.w;
    }
}

// ============ k4: per-bucket counting sort, wave-privatized histograms =====
__global__ __launch_bounds__(256) void k4_kernel(
    const unsigned* __restrict__ bpair, const int* __restrict__ bbase,
    const int* __restrict__ btot, int* __restrict__ perm,
    int* __restrict__ start, int* __restrict__ cnt)
{
    __shared__ int hw[4][64];   // per-wave histograms
    __shared__ int sc[64];      // exclusive scan of totals
    __shared__ int cuw[4][64];  // per-wave placement cursors
    const int b = blockIdx.x, tid = threadIdx.x;
    const int w = tid >> 6;
    const int jb = bbase[b], n = btot[b];
    hw[tid >> 6][tid & 63] = 0;
    __syncthreads();
    for (int i = tid; i < n; i += 256)
        atomicAdd(&hw[w][bpair[jb + i] >> 17], 1);
    __syncthreads();
    if (tid == 0) {
        int r = 0;
        for (int i = 0; i < 64; ++i) {
            int h0 = hw[0][i], h1 = hw[1][i], h2 = hw[2][i], h3 = hw[3][i];
            sc[i] = r;
            cuw[0][i] = r;
            cuw[1][i] = r + h0;
            cuw[2][i] = r + h0 + h1;
            cuw[3][i] = r + h0 + h1 + h2;
            r += h0 + h1 + h2 + h3;
        }
    }
    __syncthreads();
    if (tid < 64) {
        int dg = b * 64 + tid;
        if (dg < NDST_TOTAL) {
            start[dg] = jb + sc[tid];
            int nx = (tid < 63) ? sc[tid + 1] : n;
            cnt[dg] = nx - sc[tid];
        }
    }
    for (int i = tid; i < n; i += 256) {
        unsigned p = bpair[jb + i];
        int pos = atomicAdd(&cuw[w][p >> 17], 1);
        perm[jb + pos] = (int)(p & 0x1FFFF);
    }
}

// ============ agg: r8-proven structure + type-specialized constant strides =
// one wave per segment (interleaved), LDS sWk matvec, 32-bit offsets
template<int SS, int SOFF, int DS, int DOFF, bool SEM>
__device__ __forceinline__ void agg_range(
    int dlo, int dhi, int wave, int nwaves,
    int t, int w, int g, int l4, int hq,
    const int* __restrict__ perm, const int* __restrict__ start,
    const int* __restrict__ cnt,
    const unsigned* __restrict__ hsrc, const __half* __restrict__ ssrc,
    const __half* __restrict__ sdst,
    const float* sWk, float bkf, float (*srow)[64],
    float& pool, float& sem)
{
    for (int d = dlo + wave; d < dhi; d += nwaves) {
        unsigned ld = (unsigned)(d - dlo);
        float adst = __half2float(sdst[ld * DS + DOFF + hq]);
        int jb = start[d], je = jb + cnt[d];
        float4 acc = make_float4(0.f, 0.f, 0.f, 0.f);
        float dsum = 0.f;
        for (int j = jb; j < je; j += 8) {
            int j0 = j + g, j1 = j + 4 + g;
            bool v0 = j0 < je, v1 = j1 < je;
            unsigned s0 = (unsigned)perm[v0 ? j0 : je - 1];
            unsigned s1 = (unsigned)perm[v1 ? j1 : je - 1];
            float c0 = __half2float(ssrc[s0 * SS + (SOFF + hq)]);
            float c1 = __half2float(ssrc[s1 * SS + (SOFF + hq)]);
            unsigned u0 = hsrc[s0 * 16 + l4];
            unsigned u1 = hsrc[s1 * 16 + l4];
            float a0 = c0 + adst; a0 = a0 > 0.f ? a0 : 0.2f * a0;
            float a1 = c1 + adst; a1 = a1 > 0.f ? a1 : 0.2f * a1;
            float e0 = v0 ? __expf(a0) : 0.f;
            float e1 = v1 ? __expf(a1) : 0.f;
            dsum += e0 + e1;
            v2f lo0 = __builtin_amdgcn_cvt_pk_f32_fp8((int)u0, false);
            v2f hi0 = __builtin_amdgcn_cvt_pk_f32_fp8((int)u0, true);
            v2f lo1 = __builtin_amdgcn_cvt_pk_f32_fp8((int)u1, false);
            v2f hi1 = __builtin_amdgcn_cvt_pk_f32_fp8((int)u1, true);
            acc.x += lo0.x * e0 + lo1.x * e1;
            acc.y += lo0.y * e0 + lo1.y * e1;
            acc.z += hi0.x * e0 + hi1.x * e1;
            acc.w += hi0.y * e0 + hi1.y * e1;
        }
#pragma unroll
        for (int mask = 16; mask <= 32; mask <<= 1) {
            acc.x += __shfl_xor(acc.x, mask, 64);
            acc.y += __shfl_xor(acc.y, mask, 64);
            acc.z += __shfl_xor(acc.z, mask, 64);
            acc.w += __shfl_xor(acc.w, mask, 64);
            dsum  += __shfl_xor(dsum,  mask, 64);
        }
        float inv = 1.f / (dsum + 1e-16f);
        float4 v4 = make_float4(fmaxf(acc.x * inv, 0.f), fmaxf(acc.y * inv, 0.f),
                                fmaxf(acc.z * inv, 0.f), fmaxf(acc.w * inv, 0.f));
        if (g == 0) *(float4*)&srow[w][l4 * 4] = v4;  // rebroadcast layout
        float v = srow[w][t];                          // wave-coherent LDS
        pool += v;
        if (SEM) {
            float a2 = bkf;
#pragma unroll
            for (int k = 0; k < 64; ++k) a2 += srow[w][k] * sWk[k * 64 + t];
            sem += tanhf(a2);
        }
    }
}

__global__ __launch_bounds__(256) void agg_all_kernel(
    const int* __restrict__ perm, const int* __restrict__ start,
    const int* __restrict__ cnt,
    const unsigned* __restrict__ h8_ing, const unsigned* __restrict__ h8_dir,
    const __half* __restrict__ s_ing, const __half* __restrict__ s_dir,
    const float* __restrict__ Wk, const float* __restrict__ bk,
    float* __restrict__ pool_ing, float* __restrict__ pool_dir,
    float* __restrict__ sem_dir)
{
    __shared__ float sWk[64 * 64];
    __shared__ float srow[4][64];
    __shared__ float sred[4][64];
    const int t = threadIdx.x & 63, w = threadIdx.x >> 6;
    const int g  = t >> 4;       // edge group 0..3
    const int l4 = t & 15;       // feature quad: 4*l4 .. 4*l4+3
    const int hq = l4 >> 2;      // head of my features
    for (int i = threadIdx.x; i < 4096; i += 256) sWk[i] = Wk[i];
    const float bkf = bk[t];
    float p_ing = 0.f, dummy = 0.f;
    float p0 = 0.f, p1 = 0.f, p2 = 0.f, p3 = 0.f;
    float m0 = 0.f, m1 = 0.f, m2 = 0.f, m3 = 0.f;
    __syncthreads();
    const int nwaves = gridDim.x * 4;
    const int wave = blockIdx.x * 4 + w;
    // type-specialized ranges (constant strides -> cheap 32-bit addressing)
    agg_range<12, 0, 28, 0,  true>(0,      50000,  wave, nwaves, t, w, g, l4, hq,
        perm, start, cnt, h8_ing, s_ing, s_dir, sWk, bkf, srow, p0, m0);       // cooc
    agg_range<12, 4, 28, 4,  true>(50000,  100000, wave, nwaves, t, w, g, l4, hq,
        perm, start, cnt, h8_ing, s_ing, s_dir, sWk, bkf, srow, p1, m1);       // used
    agg_range<28, 8, 12, 8,  false>(100000, 200000, wave, nwaves, t, w, g, l4, hq,
        perm, start, cnt, h8_dir, s_dir, s_ing, sWk, bkf, srow, p_ing, dummy); // contains
    agg_range<28, 12, 28, 16, true>(200000, 250000, wave, nwaves, t, w, g, l4, hq,
        perm, start, cnt, h8_dir, s_dir, s_dir, sWk, bkf, srow, p2, m2);       // pairs
    agg_range<28, 20, 28, 24, true>(250000, 300000, wave, nwaves, t, w, g, l4, hq,
        perm, start, cnt, h8_dir, s_dir, s_dir, sWk, bkf, srow, p3, m3);       // follows

    float vals[9] = { p_ing, p0, p1, p2, p3, m0, m1, m2, m3 };
    float* outs[9] = { pool_ing, pool_dir, pool_dir + 64, pool_dir + 128,
                       pool_dir + 192, sem_dir, sem_dir + 64, sem_dir + 128,
                       sem_dir + 192 };
    for (int i = 0; i < 9; ++i) {
        __syncthreads();
        sred[w][t] = vals[i];
        __syncthreads();
        if (w == 0)
            atomicAdd(&outs[i][t], sred[0][t] + sred[1][t] + sred[2][t] + sred[3][t]);
    }
}

// ============ final: semantic softmax + pools + VAE head ===================
__global__ __launch_bounds__(64) void final_kernel(
    const float* __restrict__ pool_ing, const float* __restrict__ pool_dir,
    const float* __restrict__ sem_dir, const float* __restrict__ q,
    const float* __restrict__ cond, const float* __restrict__ eps,
    const float* __restrict__ W_mu, const float* __restrict__ b_mu,
    const float* __restrict__ W_lv, const float* __restrict__ b_lv,
    const float* __restrict__ W_fc3, const float* __restrict__ b_fc3,
    const float* __restrict__ W_fc2, const float* __restrict__ b_fc2,
    float* __restrict__ out)
{
    __shared__ float gr[136];
    __shared__ float sc[4], attn[4];
    __shared__ float z[32], hfc[64];
    int t = threadIdx.x;  // 64 threads
    if (t < 4) {
        float s = 0.f;
        for (int f = 0; f < 64; ++f)
            s += (sem_dir[t * 64 + f] / (float)N_DIR) * q[f];
        sc[t] = s;
    }
    gr[t] = pool_ing[t] / (float)N_ING;   // out_ing == o_cont (T=1 softmax)
    __syncthreads();
    if (t == 0) {
        float m = fmaxf(fmaxf(sc[0], sc[1]), fmaxf(sc[2], sc[3]));
        float ssum = 0.f;
        for (int i = 0; i < 4; ++i) { attn[i] = expf(sc[i] - m); ssum += attn[i]; }
        for (int i = 0; i < 4; ++i) attn[i] /= ssum;
    }
    __syncthreads();
    {
        float v = 0.f;
        for (int tt = 0; tt < 4; ++tt)
            v += attn[tt] * (pool_dir[tt * 64 + t] / (float)N_DIR);
        gr[64 + t] = v;
    }
    if (t < 8) gr[128 + t] = cond[t];
    __syncthreads();
    if (t < 32) {
        float m = b_mu[t], lv = b_lv[t];
        for (int i = 0; i < 136; ++i) {
            float g = gr[i];
            m  += g * W_mu[i * 32 + t];
            lv += g * W_lv[i * 32 + t];
        }
        out[16 + t] = m;
        out[48 + t] = lv;
        z[t] = m + eps[t] * expf(0.5f * lv);
    }
    __syncthreads();
    {
        float v = b_fc3[t];
        for (int j = 0; j < 32; ++j) v += z[j] * W_fc3[j * 64 + t];
        hfc[t] = fmaxf(v, 0.f);
    }
    __syncthreads();
    if (t < 16) {
        float v = b_fc2[t];
        for (int f = 0; f < 64; ++f) v += hfc[f] * W_fc2[f * 16 + t];
        out[t] = tanhf(v);
    }
}

extern "C" void kernel_launch(void* const* d_in, const int* in_sizes, int n_in,
                              void* d_out, int out_size, void* d_ws, size_t ws_size,
                              hipStream_t stream) {
    const float* x_ing = (const float*)d_in[0];
    const float* x_dir = (const float*)d_in[1];
    const float* cond  = (const float*)d_in[2];
    const float* eps   = (const float*)d_in[3];
    const int* ei_cooc     = (const int*)d_in[4];
    const int* ei_used     = (const int*)d_in[5];
    const int* ei_contains = (const int*)d_in[6];
    const int* ei_pairs    = (const int*)d_in[7];
    const int* ei_follows  = (const int*)d_in[8];
    const float* W_pi = (const float*)d_in[9];
    const float* b_pi = (const float*)d_in[10];
    const float* W_pd = (const float*)d_in[11];
    const float* b_pd = (const float*)d_in[12];
    const float* Wk   = (const float*)d_in[13];
    const float* bk   = (const float*)d_in[14];
    const float* q    = (const float*)d_in[15];
    const float* W_mu = (const float*)d_in[16];
    const float* b_mu = (const float*)d_in[17];
    const float* W_lv = (const float*)d_in[18];
    const float* b_lv = (const float*)d_in[19];
    const float* W_fc3 = (const float*)d_in[20];
    const float* b_fc3 = (const float*)d_in[21];
    const float* W_fc2 = (const float*)d_in[22];
    const float* b_fc2 = (const float*)d_in[23];
    const float* as_cooc     = (const float*)d_in[24];
    const float* ad_cooc     = (const float*)d_in[25];
    const float* as_used     = (const float*)d_in[26];
    const float* ad_used     = (const float*)d_in[27];
    const float* as_contains = (const float*)d_in[28];
    const float* ad_contains = (const float*)d_in[29];
    const float* as_pairs    = (const float*)d_in[30];
    const float* ad_pairs    = (const float*)d_in[31];
    const float* as_follows  = (const float*)d_in[32];
    const float* ad_follows  = (const float*)d_in[33];

    // ---- workspace layout ----
    unsigned* bpair = (unsigned*)d_ws;                        // 5M u32 (20 MB)
    unsigned* h8_ing = bpair + (size_t)5 * NE;                // N_ING*16 u32
    unsigned* h8_dir = h8_ing + (size_t)N_ING * 16;           // N_DIR*16
    __half* s_ing = (__half*)(h8_dir + (size_t)N_DIR * 16);   // N_ING*12 fp16
    __half* s_dir = s_ing + (size_t)N_ING * 12;               // N_DIR*28 fp16
    int*   perm  = (int*)(s_dir + (size_t)N_DIR * 28);        // 5M
    int*   blockcnt  = perm + (size_t)5 * NE;                 // 80*4688
    int*   blockbase = blockcnt + (size_t)NBK * NBUCK;        // 80*4688
    int*   bbase  = blockbase + (size_t)NBK * NBUCK;          // 4688
    int*   btot   = bbase + NBUCK;                            // 4688
    int*   start  = btot + NBUCK;                             // 300K
    int*   cnt    = start + NDST_TOTAL;                       // 300K
    int*   cursor = cnt + NDST_TOTAL;                         // 1  (zeroed region)
    float* pool_ing = (float*)(cursor + 1);                   // 64
    float* pool_dir = pool_ing + 64;                          // 4*64
    float* sem_dir  = pool_dir + 256;                         // 4*64

    // tiny memset: cursor + pools
    hipMemsetAsync(cursor, 0, (1 + 64 + 256 + 256) * sizeof(int), stream);

    // kA: bucket histogram (LDS-only atomics) + fused proj/fp8/fp16-score
    kA_kernel<<<NBK + PB_ING + PB_DIR, 256, 0, stream>>>(
        ei_cooc, ei_used, ei_contains, ei_pairs, ei_follows, blockcnt,
        x_ing, W_pi, b_pi, as_cooc, as_used, ad_contains, h8_ing, s_ing,
        x_dir, W_pd, b_pd, ad_cooc, ad_used, as_contains, as_pairs, ad_pairs,
        as_follows, ad_follows, h8_dir, s_dir);

    // k2: bucket scan -> bases (64 buckets x 4 threads per block)
    k2_kernel<<<(NBUCK + 63) / 64, 256, 0, stream>>>(
        blockcnt, blockbase, bbase, btot, cursor);

    // k3: bucket scatter (LDS cursors, u32 packed)
    k3_kernel<<<NBK, 256, 0, stream>>>(
        ei_cooc, ei_used, ei_contains, ei_pairs, ei_follows, blockbase, bpair);

    // k4: per-bucket counting sort -> perm + start/cnt
    k4_kernel<<<NBUCK, 256, 0, stream>>>(bpair, bbase, btot, perm, start, cnt);

    // agg over all 300K dst segments (interleaved waves, type-specialized)
    agg_all_kernel<<<2048, 256, 0, stream>>>(
        perm, start, cnt, h8_ing, h8_dir, s_ing, s_dir, Wk, bk,
        pool_ing, pool_dir, sem_dir);

    final_kernel<<<1, 64, 0, stream>>>(
        pool_ing, pool_dir, sem_dir, q, cond, eps,
        W_mu, b_mu, W_lv, b_lv, W_fc3, b_fc3, W_fc2, b_fc2, (float*)d_out);
}

// Round 13
// 548.042 us; speedup vs baseline: 2.2206x; 1.1059x over previous
//
#include <hip/hip_runtime.h>
#include <hip/hip_fp16.h>
#include <math.h>

#define N_ING 100000
#define N_DIR 50000
#define NE    1000000
#define NDST_TOTAL 300000   // 50K(cooc)+50K(used)+100K(contains)+50K(pairs)+50K(follows)
#define NBUCK 4688          // ceil(300000/64): 64 dst nodes per bucket
#define BA    16            // hist/scatter blocks per edge type
#define NBK   (5 * BA)      // 80
#define I4PT  (NE / 4)      // int4s per type
#define PB_ING 384
#define PB_DIR 192

typedef float v2f __attribute__((ext_vector_type(2)));

// ============ kA: bucket histogram (LDS atomics) + fused proj+score ========
__global__ __launch_bounds__(256) void kA_kernel(
    const int* __restrict__ e0, const int* __restrict__ e1,
    const int* __restrict__ e2, const int* __restrict__ e3,
    const int* __restrict__ e4, int* __restrict__ blockcnt,
    const float* __restrict__ x_ing, const float* __restrict__ W_pi,
    const float* __restrict__ b_pi,
    const float* __restrict__ as_cooc, const float* __restrict__ as_used,
    const float* __restrict__ ad_contains,
    unsigned* __restrict__ h8_ing, __half* __restrict__ s_ing,
    const float* __restrict__ x_dir, const float* __restrict__ W_pd,
    const float* __restrict__ b_pd,
    const float* __restrict__ ad_cooc, const float* __restrict__ ad_used,
    const float* __restrict__ as_contains, const float* __restrict__ as_pairs,
    const float* __restrict__ ad_pairs, const float* __restrict__ as_follows,
    const float* __restrict__ ad_follows,
    unsigned* __restrict__ h8_dir, __half* __restrict__ s_dir)
{
    __shared__ int hist[NBUCK];
    __shared__ float sW[16 * 64];
    __shared__ float sbb[64];
    __shared__ float satt[7 * 64];
    __shared__ float sx[4][16];
    __shared__ float srow[4][64];

    const int bid = blockIdx.x;
    const int tid = threadIdx.x;
    if (bid < NBK) {
        // ---------- bucket histogram, one row per block ----------
        const int type = bid / BA, blk = bid % BA;
        const int* ei = type == 0 ? e0 : type == 1 ? e1 : type == 2 ? e2
                      : type == 3 ? e3 : e4;
        const int base = type == 0 ? 0 : type == 1 ? 50000 : type == 2 ? 100000
                       : type == 3 ? 200000 : 250000;
        for (int i = tid; i < NBUCK; i += 256) hist[i] = 0;
        __syncthreads();
        const int4* d4 = (const int4*)(ei + NE);
        for (int i = blk * 256 + tid; i < I4PT; i += BA * 256) {
            int4 d = d4[i];
            atomicAdd(&hist[(base + d.x) >> 6], 1);
            atomicAdd(&hist[(base + d.y) >> 6], 1);
            atomicAdd(&hist[(base + d.z) >> 6], 1);
            atomicAdd(&hist[(base + d.w) >> 6], 1);
        }
        __syncthreads();
        int* row = blockcnt + (size_t)bid * NBUCK;
        for (int i = tid; i < NBUCK; i += 256) row[i] = hist[i];
    } else if (bid < NBK + PB_ING) {
        // ---------- proj + fp8 pack + fp16 scores, ingredient nodes ---------
        const int g = tid >> 6, t = tid & 63;
        for (int i = tid; i < 16 * 64; i += 256) sW[i] = W_pi[i];
        if (tid < 64) {
            sbb[tid] = b_pi[tid];
            satt[tid]       = as_cooc[tid];
            satt[64 + tid]  = as_used[tid];
            satt[128 + tid] = ad_contains[tid];
        }
        __syncthreads();
        for (int q = bid - NBK; q < N_ING / 4; q += PB_ING) {
            int n = q * 4 + g;
            if (t < 16) sx[g][t] = x_ing[(size_t)n * 16 + t];
            __syncthreads();
            float s = sbb[t];
#pragma unroll
            for (int i = 0; i < 16; ++i) s += sx[g][i] * sW[i * 64 + t];
            srow[g][t] = s;
            __syncthreads();
            if (t < 16) {
                int w0 = __builtin_amdgcn_cvt_pk_fp8_f32(srow[g][t * 4], srow[g][t * 4 + 1], 0, false);
                int w  = __builtin_amdgcn_cvt_pk_fp8_f32(srow[g][t * 4 + 2], srow[g][t * 4 + 3], w0, true);
                h8_ing[(size_t)n * 16 + t] = (unsigned)w;
            }
            if (t < 12) {
                int slot = t >> 2, hh = t & 3;
                float sc = 0.f;
#pragma unroll
                for (int d = 0; d < 16; ++d)
                    sc += srow[g][hh * 16 + d] * satt[slot * 64 + hh * 16 + d];
                s_ing[(size_t)n * 12 + t] = __float2half(sc);
            }
            __syncthreads();
        }
    } else {
        // ---------- proj + fp8 pack + fp16 scores, direction nodes ----------
        const int g = tid >> 6, t = tid & 63;
        for (int i = tid; i < 8 * 64; i += 256) sW[i] = W_pd[i];
        if (tid < 64) {
            sbb[tid] = b_pd[tid];
            satt[tid]        = ad_cooc[tid];
            satt[64  + tid]  = ad_used[tid];
            satt[128 + tid]  = as_contains[tid];
            satt[192 + tid]  = as_pairs[tid];
            satt[256 + tid]  = ad_pairs[tid];
            satt[320 + tid]  = as_follows[tid];
            satt[384 + tid]  = ad_follows[tid];
        }
        __syncthreads();
        for (int q = bid - NBK - PB_ING; q < N_DIR / 4; q += PB_DIR) {
            int n = q * 4 + g;
            if (t < 8) sx[g][t] = x_dir[(size_t)n * 8 + t];
            __syncthreads();
            float s = sbb[t];
#pragma unroll
            for (int i = 0; i < 8; ++i) s += sx[g][i] * sW[i * 64 + t];
            srow[g][t] = s;
            __syncthreads();
            if (t < 16) {
                int w0 = __builtin_amdgcn_cvt_pk_fp8_f32(srow[g][t * 4], srow[g][t * 4 + 1], 0, false);
                int w  = __builtin_amdgcn_cvt_pk_fp8_f32(srow[g][t * 4 + 2], srow[g][t * 4 + 3], w0, true);
                h8_dir[(size_t)n * 16 + t] = (unsigned)w;
            }
            if (t < 28) {
                int slot = t >> 2, hh = t & 3;
                float sc = 0.f;
#pragma unroll
                for (int d = 0; d < 16; ++d)
                    sc += srow[g][hh * 16 + d] * satt[slot * 64 + hh * 16 + d];
                s_dir[(size_t)n * 28 + t] = __float2half(sc);
            }
            __syncthreads();
        }
    }
}

// ============ k2: bucket totals + bases, 64 buckets x 4 threads per block ==
__global__ __launch_bounds__(256) void k2_kernel(
    const int* __restrict__ blockcnt, int* __restrict__ blockbase,
    int* __restrict__ bbase, int* __restrict__ btot, int* __restrict__ cursor)
{
    __shared__ int part[4][64];
    __shared__ int tots[64];
    __shared__ int scn[64];
    __shared__ int bw;
    const int tid = threadIdx.x;
    const int kq = tid >> 6, bl = tid & 63;   // 4 k-quarters x 64 buckets
    const int b = blockIdx.x * 64 + bl;
    const int K = NBK / 4;                    // 20 rows per quarter
    int ps = 0;
    if (b < NBUCK)
        for (int k = kq * K; k < kq * K + K; ++k)
            ps += blockcnt[(size_t)k * NBUCK + b];
    part[kq][bl] = ps;
    __syncthreads();
    if (tid < 64) {
        int t = part[0][tid] + part[1][tid] + part[2][tid] + part[3][tid];
        tots[tid] = t;
        scn[tid] = t;
    }
    __syncthreads();
    for (int off = 1; off < 64; off <<= 1) {
        int v = 0;
        if (tid < 64 && tid >= off) v = scn[tid - off];
        __syncthreads();
        if (tid < 64) scn[tid] += v;
        __syncthreads();
    }
    if (tid == 63) bw = atomicAdd(cursor, scn[63]);
    __syncthreads();
    if (b < NBUCK) {
        int bs = bw + scn[bl] - tots[bl];     // exclusive bucket base
        if (kq == 0) {
            bbase[b] = bs;
            btot[b] = tots[bl];
        }
        int run = bs;
        for (int q = 0; q < kq; ++q) run += part[q][bl];
        for (int k = kq * K; k < kq * K + K; ++k) {
            blockbase[(size_t)k * NBUCK + b] = run;
            run += blockcnt[(size_t)k * NBUCK + b];
        }
    }
}

// ============ k3: bucket scatter (LDS cursors, packed u32 entries) =========
__global__ __launch_bounds__(256) void k3_kernel(
    const int* __restrict__ e0, const int* __restrict__ e1,
    const int* __restrict__ e2, const int* __restrict__ e3,
    const int* __restrict__ e4, const int* __restrict__ blockbase,
    unsigned* __restrict__ bpair)
{
    __shared__ int cur[NBUCK];
    const int bid = blockIdx.x, tid = threadIdx.x;
    const int type = bid / BA, blk = bid % BA;
    const int* ei = type == 0 ? e0 : type == 1 ? e1 : type == 2 ? e2
                  : type == 3 ? e3 : e4;
    const int base = type == 0 ? 0 : type == 1 ? 50000 : type == 2 ? 100000
                   : type == 3 ? 200000 : 250000;
    const int* row = blockbase + (size_t)bid * NBUCK;
    for (int i = tid; i < NBUCK; i += 256) cur[i] = row[i];
    __syncthreads();
    const int4* s4 = (const int4*)ei;
    const int4* d4 = (const int4*)(ei + NE);
    for (int i = blk * 256 + tid; i < I4PT; i += BA * 256) {
        int4 s = s4[i];
        int4 d = d4[i];
        int g0 = base + d.x, g1 = base + d.y, g2 = base + d.z, g3 = base + d.w;
        int p0 = atomicAdd(&cur[g0 >> 6], 1);
        int p1 = atomicAdd(&cur[g1 >> 6], 1);
        int p2 = atomicAdd(&cur[g2 >> 6], 1);
        int p3 = atomicAdd(&cur[g3 >> 6], 1);
        bpair[p0] = ((unsigned)(g0 & 63) << 17) | (unsigned)s.x;
        bpair[p1] = ((unsigned)(g1 & 63) << 17) | (unsigned)s.y;
        bpair[p2] = ((unsigned)(g2 & 63) << 17) | (unsigned)s.z;
        bpair[p3] = ((unsigned)(g3 & 63) << 17) | (unsigned)s.w;
    }
}

// ============ k4: per-bucket counting sort -> perm + start/cnt =============
__global__ __launch_bounds__(256) void k4_kernel(
    const unsigned* __restrict__ bpair, const int* __restrict__ bbase,
    const int* __restrict__ btot, int* __restrict__ perm,
    int* __restrict__ start, int* __restrict__ cnt)
{
    __shared__ int h[64], sc[64], cu[64];
    const int b = blockIdx.x, tid = threadIdx.x;
    const int jb = bbase[b], n = btot[b];
    if (tid < 64) h[tid] = 0;
    __syncthreads();
    for (int i = tid; i < n; i += 256)
        atomicAdd(&h[bpair[jb + i] >> 17], 1);
    __syncthreads();
    if (tid == 0) {
        int r = 0;
        for (int i = 0; i < 64; ++i) { sc[i] = r; cu[i] = r; r += h[i]; }
    }
    __syncthreads();
    if (tid < 64) {
        int dg = b * 64 + tid;
        if (dg < NDST_TOTAL) {
            start[dg] = jb + sc[tid];
            cnt[dg] = h[tid];
        }
    }
    for (int i = tid; i < n; i += 256) {
        unsigned p = bpair[jb + i];
        int pos = atomicAdd(&cu[p >> 17], 1);
        perm[jb + pos] = (int)(p & 0x1FFFF);
    }
}

// ============ fused aggregation: fp8 rows, fp16 scores, 8 edges/iter =======
__global__ __launch_bounds__(256) void agg_all_kernel(
    const int* __restrict__ perm, const int* __restrict__ start,
    const int* __restrict__ cnttot,
    const unsigned* __restrict__ h8_ing, const unsigned* __restrict__ h8_dir,
    const __half* __restrict__ s_ing, const __half* __restrict__ s_dir,
    const float* __restrict__ Wk, const float* __restrict__ bk,
    float* __restrict__ pool_ing, float* __restrict__ pool_dir,
    float* __restrict__ sem_dir)
{
    __shared__ float sWk[64 * 64];
    __shared__ float srow[4][64];
    __shared__ float sred[4][64];
    const int t = threadIdx.x & 63, w = threadIdx.x >> 6;
    const int g  = t >> 4;       // edge group 0..3
    const int l4 = t & 15;       // feature quad: 4*l4 .. 4*l4+3
    const int hq = l4 >> 2;      // head of my features
    for (int i = threadIdx.x; i < 4096; i += 256) sWk[i] = Wk[i];
    const float bkf = bk[t];
    float p_ing = 0.f;
    float p0 = 0.f, p1 = 0.f, p2 = 0.f, p3 = 0.f;
    float m0 = 0.f, m1 = 0.f, m2 = 0.f, m3 = 0.f;
    __syncthreads();
    const int nwaves = gridDim.x * 4;
    for (int d = blockIdx.x * 4 + w; d < NDST_TOTAL; d += nwaves) {
        int type, ld;
        const __half *ssrc, *sdst;
        const unsigned* hsrc;
        int ss, soff, ds, doff;
        if (d < 50000)       { type = 0; ld = d;          ssrc = s_ing; ss = 12; soff = 0;  sdst = s_dir; ds = 28; doff = 0;  hsrc = h8_ing; }
        else if (d < 100000) { type = 1; ld = d - 50000;  ssrc = s_ing; ss = 12; soff = 4;  sdst = s_dir; ds = 28; doff = 4;  hsrc = h8_ing; }
        else if (d < 200000) { type = 2; ld = d - 100000; ssrc = s_dir; ss = 28; soff = 8;  sdst = s_ing; ds = 12; doff = 8;  hsrc = h8_dir; }
        else if (d < 250000) { type = 3; ld = d - 200000; ssrc = s_dir; ss = 28; soff = 12; sdst = s_dir; ds = 28; doff = 16; hsrc = h8_dir; }
        else                 { type = 4; ld = d - 250000; ssrc = s_dir; ss = 28; soff = 20; sdst = s_dir; ds = 28; doff = 24; hsrc = h8_dir; }
        float adst = __half2float(sdst[(size_t)ld * ds + doff + hq]);
        int jb = start[d], je = jb + cnttot[d];
        float4 acc = make_float4(0.f, 0.f, 0.f, 0.f);
        float dsum = 0.f;
        for (int j = jb; j < je; j += 8) {
            int j0 = j + g, j1 = j + 4 + g;
            bool v0 = j0 < je, v1 = j1 < je;
            int s0 = perm[v0 ? j0 : je - 1];
            int s1 = perm[v1 ? j1 : je - 1];
            float c0 = __half2float(ssrc[(size_t)s0 * ss + soff + hq]);
            float c1 = __half2float(ssrc[(size_t)s1 * ss + soff + hq]);
            unsigned u0 = hsrc[(size_t)s0 * 16 + l4];
            unsigned u1 = hsrc[(size_t)s1 * 16 + l4];
            float a0 = c0 + adst; a0 = a0 > 0.f ? a0 : 0.2f * a0;
            float a1 = c1 + adst; a1 = a1 > 0.f ? a1 : 0.2f * a1;
            float e0 = v0 ? __expf(a0) : 0.f;
            float e1 = v1 ? __expf(a1) : 0.f;
            dsum += e0 + e1;
            v2f lo0 = __builtin_amdgcn_cvt_pk_f32_fp8((int)u0, false);
            v2f hi0 = __builtin_amdgcn_cvt_pk_f32_fp8((int)u0, true);
            v2f lo1 = __builtin_amdgcn_cvt_pk_f32_fp8((int)u1, false);
            v2f hi1 = __builtin_amdgcn_cvt_pk_f32_fp8((int)u1, true);
            acc.x += lo0.x * e0 + lo1.x * e1;
            acc.y += lo0.y * e0 + lo1.y * e1;
            acc.z += hi0.x * e0 + hi1.x * e1;
            acc.w += hi0.y * e0 + hi1.y * e1;
        }
#pragma unroll
        for (int mask = 16; mask <= 32; mask <<= 1) {
            acc.x += __shfl_xor(acc.x, mask, 64);
            acc.y += __shfl_xor(acc.y, mask, 64);
            acc.z += __shfl_xor(acc.z, mask, 64);
            acc.w += __shfl_xor(acc.w, mask, 64);
            dsum  += __shfl_xor(dsum,  mask, 64);
        }
        float inv = 1.f / (dsum + 1e-16f);
        float4 v4 = make_float4(fmaxf(acc.x * inv, 0.f), fmaxf(acc.y * inv, 0.f),
                                fmaxf(acc.z * inv, 0.f), fmaxf(acc.w * inv, 0.f));
        if (g == 0) *(float4*)&srow[w][l4 * 4] = v4;  // rebroadcast layout
        float v = srow[w][t];                          // wave-coherent LDS
        if (type == 2) {
            p_ing += v;
        } else {
            float a2 = bkf;
#pragma unroll
            for (int k = 0; k < 64; ++k) a2 += srow[w][k] * sWk[k * 64 + t];
            float tv = tanhf(a2);
            if (type == 0)      { p0 += v; m0 += tv; }
            else if (type == 1) { p1 += v; m1 += tv; }
            else if (type == 3) { p2 += v; m2 += tv; }
            else                { p3 += v; m3 += tv; }
        }
    }
    float vals[9] = { p_ing, p0, p1, p2, p3, m0, m1, m2, m3 };
    float* outs[9] = { pool_ing, pool_dir, pool_dir + 64, pool_dir + 128,
                       pool_dir + 192, sem_dir, sem_dir + 64, sem_dir + 128,
                       sem_dir + 192 };
    for (int i = 0; i < 9; ++i) {
        __syncthreads();
        sred[w][t] = vals[i];
        __syncthreads();
        if (w == 0)
            atomicAdd(&outs[i][t], sred[0][t] + sred[1][t] + sred[2][t] + sred[3][t]);
    }
}

// ============ final: semantic softmax + pools + VAE head ===================
__global__ __launch_bounds__(64) void final_kernel(
    const float* __restrict__ pool_ing, const float* __restrict__ pool_dir,
    const float* __restrict__ sem_dir, const float* __restrict__ q,
    const float* __restrict__ cond, const float* __restrict__ eps,
    const float* __restrict__ W_mu, const float* __restrict__ b_mu,
    const float* __restrict__ W_lv, const float* __restrict__ b_lv,
    const float* __restrict__ W_fc3, const float* __restrict__ b_fc3,
    const float* __restrict__ W_fc2, const float* __restrict__ b_fc2,
    float* __restrict__ out)
{
    __shared__ float gr[136];
    __shared__ float sc[4], attn[4];
    __shared__ float z[32], hfc[64];
    int t = threadIdx.x;  // 64 threads
    if (t < 4) {
        float s = 0.f;
        for (int f = 0; f < 64; ++f)
            s += (sem_dir[t * 64 + f] / (float)N_DIR) * q[f];
        sc[t] = s;
    }
    gr[t] = pool_ing[t] / (float)N_ING;   // out_ing == o_cont (T=1 softmax)
    __syncthreads();
    if (t == 0) {
        float m = fmaxf(fmaxf(sc[0], sc[1]), fmaxf(sc[2], sc[3]));
        float ssum = 0.f;
        for (int i = 0; i < 4; ++i) { attn[i] = expf(sc[i] - m); ssum += attn[i]; }
        for (int i = 0; i < 4; ++i) attn[i] /= ssum;
    }
    __syncthreads();
    {
        float v = 0.f;
        for (int tt = 0; tt < 4; ++tt)
            v += attn[tt] * (pool_dir[tt * 64 + t] / (float)N_DIR);
        gr[64 + t] = v;
    }
    if (t < 8) gr[128 + t] = cond[t];
    __syncthreads();
    if (t < 32) {
        float m = b_mu[t], lv = b_lv[t];
        for (int i = 0; i < 136; ++i) {
            float g = gr[i];
            m  += g * W_mu[i * 32 + t];
            lv += g * W_lv[i * 32 + t];
        }
        out[16 + t] = m;
        out[48 + t] = lv;
        z[t] = m + eps[t] * expf(0.5f * lv);
    }
    __syncthreads();
    {
        float v = b_fc3[t];
        for (int j = 0; j < 32; ++j) v += z[j] * W_fc3[j * 64 + t];
        hfc[t] = fmaxf(v, 0.f);
    }
    __syncthreads();
    if (t < 16) {
        float v = b_fc2[t];
        for (int f = 0; f < 64; ++f) v += hfc[f] * W_fc2[f * 16 + t];
        out[t] = tanhf(v);
    }
}

extern "C" void kernel_launch(void* const* d_in, const int* in_sizes, int n_in,
                              void* d_out, int out_size, void* d_ws, size_t ws_size,
                              hipStream_t stream) {
    const float* x_ing = (const float*)d_in[0];
    const float* x_dir = (const float*)d_in[1];
    const float* cond  = (const float*)d_in[2];
    const float* eps   = (const float*)d_in[3];
    const int* ei_cooc     = (const int*)d_in[4];
    const int* ei_used     = (const int*)d_in[5];
    const int* ei_contains = (const int*)d_in[6];
    const int* ei_pairs    = (const int*)d_in[7];
    const int* ei_follows  = (const int*)d_in[8];
    const float* W_pi = (const float*)d_in[9];
    const float* b_pi = (const float*)d_in[10];
    const float* W_pd = (const float*)d_in[11];
    const float* b_pd = (const float*)d_in[12];
    const float* Wk   = (const float*)d_in[13];
    const float* bk   = (const float*)d_in[14];
    const float* q    = (const float*)d_in[15];
    const float* W_mu = (const float*)d_in[16];
    const float* b_mu = (const float*)d_in[17];
    const float* W_lv = (const float*)d_in[18];
    const float* b_lv = (const float*)d_in[19];
    const float* W_fc3 = (const float*)d_in[20];
    const float* b_fc3 = (const float*)d_in[21];
    const float* W_fc2 = (const float*)d_in[22];
    const float* b_fc2 = (const float*)d_in[23];
    const float* as_cooc     = (const float*)d_in[24];
    const float* ad_cooc     = (const float*)d_in[25];
    const float* as_used     = (const float*)d_in[26];
    const float* ad_used     = (const float*)d_in[27];
    const float* as_contains = (const float*)d_in[28];
    const float* ad_contains = (const float*)d_in[29];
    const float* as_pairs    = (const float*)d_in[30];
    const float* ad_pairs    = (const float*)d_in[31];
    const float* as_follows  = (const float*)d_in[32];
    const float* ad_follows  = (const float*)d_in[33];

    // ---- workspace layout ----
    unsigned* bpair = (unsigned*)d_ws;                        // 5M u32 (20 MB)
    unsigned* h8_ing = bpair + (size_t)5 * NE;                // N_ING*16 u32
    unsigned* h8_dir = h8_ing + (size_t)N_ING * 16;           // N_DIR*16
    __half* s_ing = (__half*)(h8_dir + (size_t)N_DIR * 16);   // N_ING*12 fp16
    __half* s_dir = s_ing + (size_t)N_ING * 12;               // N_DIR*28 fp16
    int*   perm  = (int*)(s_dir + (size_t)N_DIR * 28);        // 5M
    int*   blockcnt  = perm + (size_t)5 * NE;                 // 80*4688
    int*   blockbase = blockcnt + (size_t)NBK * NBUCK;        // 80*4688
    int*   bbase  = blockbase + (size_t)NBK * NBUCK;          // 4688
    int*   btot   = bbase + NBUCK;                            // 4688
    int*   start  = btot + NBUCK;                             // 300K
    int*   cnt    = start + NDST_TOTAL;                       // 300K
    int*   cursor = cnt + NDST_TOTAL;                         // 1  (zeroed region)
    float* pool_ing = (float*)(cursor + 1);                   // 64
    float* pool_dir = pool_ing + 64;                          // 4*64
    float* sem_dir  = pool_dir + 256;                         // 4*64

    // tiny memset: cursor + pools
    hipMemsetAsync(cursor, 0, (1 + 64 + 256 + 256) * sizeof(int), stream);

    // kA: bucket histogram (LDS-only atomics) + fused proj/fp8/fp16-score
    kA_kernel<<<NBK + PB_ING + PB_DIR, 256, 0, stream>>>(
        ei_cooc, ei_used, ei_contains, ei_pairs, ei_follows, blockcnt,
        x_ing, W_pi, b_pi, as_cooc, as_used, ad_contains, h8_ing, s_ing,
        x_dir, W_pd, b_pd, ad_cooc, ad_used, as_contains, as_pairs, ad_pairs,
        as_follows, ad_follows, h8_dir, s_dir);

    // k2: bucket scan -> bases (64 buckets x 4 threads per block)
    k2_kernel<<<(NBUCK + 63) / 64, 256, 0, stream>>>(
        blockcnt, blockbase, bbase, btot, cursor);

    // k3: bucket scatter (LDS cursors, u32 packed)
    k3_kernel<<<NBK, 256, 0, stream>>>(
        ei_cooc, ei_used, ei_contains, ei_pairs, ei_follows, blockbase, bpair);

    // k4: per-bucket counting sort -> perm + start/cnt
    k4_kernel<<<NBUCK, 256, 0, stream>>>(bpair, bbase, btot, perm, start, cnt);

    // agg over all 300K dst segments
    agg_all_kernel<<<2048, 256, 0, stream>>>(
        perm, start, cnt, h8_ing, h8_dir, s_ing, s_dir, Wk, bk,
        pool_ing, pool_dir, sem_dir);

    final_kernel<<<1, 64, 0, stream>>>(
        pool_ing, pool_dir, sem_dir, q, cond, eps,
        W_mu, b_mu, W_lv, b_lv, W_fc3, b_fc3, W_fc2, b_fc2, (float*)d_out);
}